// Round 6
// baseline (330.743 us; speedup 1.0000x reference)
//
#include <hip/hip_runtime.h>

#define HW 3136
#define WID 56
#define HEI 56
#define NCH 256
#define NB 16
#define MTOT (NB * HW)   // 50176 flat pixels

typedef __attribute__((ext_vector_type(8))) short bf16x8;
typedef __attribute__((ext_vector_type(8))) unsigned short u16x8;
typedef __attribute__((ext_vector_type(4))) float f32x4;

__device__ __forceinline__ unsigned int f2bf(float f) {
    unsigned int x = __float_as_uint(f);
    return (x + 0x7fffu + ((x >> 16) & 1u)) >> 16;  // RNE
}
__device__ __forceinline__ float bf2f(unsigned short u) {
    return __uint_as_float(((unsigned int)u) << 16);
}

// ---------------------------------------------------------------------------
// Weight conversion fp32 -> bf16 (value_w 65536, om_w 55296, out_w 65536)
// ---------------------------------------------------------------------------
__global__ __launch_bounds__(256) void cvt_weights(const float* __restrict__ vw,
                                                   const float* __restrict__ ow,
                                                   const float* __restrict__ outw,
                                                   unsigned short* __restrict__ dvw,
                                                   unsigned short* __restrict__ dow,
                                                   unsigned short* __restrict__ doutw) {
    int i = blockIdx.x * 256 + threadIdx.x;
    if (i < 65536) dvw[i] = (unsigned short)f2bf(vw[i]);
    else if (i < 120832) dow[i - 65536] = (unsigned short)f2bf(ow[i - 65536]);
    else if (i < 186368) doutw[i - 120832] = (unsigned short)f2bf(outw[i - 120832]);
}

// ---------------------------------------------------------------------------
// MFMA bf16 GEMM over flat M=50176: out[m][d] = sum_k A[m][k]*W[d][k] + b[d]
//   A_MODE 0: A fp32 NCHW; A_MODE 1: A bf16 NCHW; A_MODE 2: A bf16 flat [m][256]
//   OUT_MODE 0: fp32 flat [m][DOUT] guarded; OUT_MODE 1: bf16 flat [m][DOUT]
//   guarded; OUT_MODE 2: fp32 NCHW (float4 stores)
// Tile: BM=128 px, BN=128 ch, BK=64; 4 waves (2M x 2N), per-wave 64x64.
// LDS XOR-swizzle byte ^= (row&7)<<4 on write and read (T2).
// ---------------------------------------------------------------------------
template <int DOUT, int A_MODE, int OUT_MODE>
__global__ __launch_bounds__(256) void gemm_kernel(const void* __restrict__ Aptr,
                                                   const unsigned short* __restrict__ Bw,
                                                   const float* __restrict__ bias,
                                                   void* __restrict__ Out) {
    int bid = blockIdx.x;
    int nt = bid & 1;
    int mt = bid >> 1;            // 0..391
    int p0 = mt * 128;            // flat pixel base
    int tid = threadIdx.x;
    int lane = tid & 63;
    int wv = tid >> 6;
    int wm = wv & 1, wn = wv >> 1;
    int n0 = nt * 128;

    __shared__ __align__(16) char lds[16384 + 16384];
    char* As = lds;
    char* Bs = lds + 16384;

    int l15 = lane & 15;
    int l4 = lane >> 4;

    f32x4 acc[4][4];
    #pragma unroll
    for (int nf = 0; nf < 4; ++nf) {
        int ch = n0 + wn * 64 + nf * 16 + l15;
        float bv = (ch < DOUT) ? bias[ch] : 0.f;
        #pragma unroll
        for (int mf = 0; mf < 4; ++mf) acc[mf][nf] = (f32x4){bv, bv, bv, bv};
    }

    for (int t = 0; t < 4; ++t) {
        int k0 = t * 64;
        // ---- stage A (128 px x 64 k) ----
        if (A_MODE == 0 || A_MODE == 1) {
            int px = tid & 127, kh = tid >> 7;
            unsigned int gpix = p0 + px;
            unsigned int n = gpix / HW;
            unsigned int rem = gpix - n * HW;
            #pragma unroll
            for (int h = 0; h < 4; ++h) {
                u16x8 v;
                if (A_MODE == 0) {
                    const float* src = (const float*)Aptr + ((size_t)(n * 256 + k0 + kh * 32 + h * 8)) * HW + rem;
                    #pragma unroll
                    for (int j = 0; j < 8; ++j) v[j] = (unsigned short)f2bf(src[(size_t)j * HW]);
                } else {
                    const unsigned short* src = (const unsigned short*)Aptr + ((size_t)(n * 256 + k0 + kh * 32 + h * 8)) * HW + rem;
                    #pragma unroll
                    for (int j = 0; j < 8; ++j) v[j] = src[(size_t)j * HW];
                }
                int byte = (px * 128 + (kh * 32 + h * 8) * 2) ^ ((px & 7) << 4);
                *(u16x8*)(As + byte) = v;
            }
        } else {
            int row = tid >> 1, q = tid & 1;
            const unsigned short* src = (const unsigned short*)Aptr + (size_t)(p0 + row) * 256 + k0 + q * 32;
            #pragma unroll
            for (int h = 0; h < 4; ++h) {
                u16x8 v = *(const u16x8*)(src + h * 8);
                int byte = (row * 128 + (q * 32 + h * 8) * 2) ^ ((row & 7) << 4);
                *(u16x8*)(As + byte) = v;
            }
        }
        // ---- stage B (128 ch x 64 k) ----
        {
            int bch = tid >> 1, kh = tid & 1;
            int ch = n0 + bch;
            bool valid = (ch < DOUT);
            const unsigned short* src = Bw + (size_t)ch * 256 + k0 + kh * 32;
            #pragma unroll
            for (int q = 0; q < 4; ++q) {
                u16x8 v = (u16x8){0, 0, 0, 0, 0, 0, 0, 0};
                if (valid) v = *(const u16x8*)(src + q * 8);
                int byte = (bch * 128 + (kh * 32 + q * 8) * 2) ^ ((bch & 7) << 4);
                *(u16x8*)(Bs + byte) = v;
            }
        }
        __syncthreads();
        // ---- compute ----
        bf16x8 af[4][2], bfr[4][2];
        #pragma unroll
        for (int mf = 0; mf < 4; ++mf)
            #pragma unroll
            for (int kf = 0; kf < 2; ++kf) {
                int row = wm * 64 + mf * 16 + l15;
                int byte = (row * 128 + (kf * 32 + l4 * 8) * 2) ^ ((row & 7) << 4);
                af[mf][kf] = *(bf16x8*)(As + byte);
            }
        #pragma unroll
        for (int nf = 0; nf < 4; ++nf)
            #pragma unroll
            for (int kf = 0; kf < 2; ++kf) {
                int row = wn * 64 + nf * 16 + l15;
                int byte = (row * 128 + (kf * 32 + l4 * 8) * 2) ^ ((row & 7) << 4);
                bfr[nf][kf] = *(bf16x8*)(Bs + byte);
            }
        #pragma unroll
        for (int mf = 0; mf < 4; ++mf)
            #pragma unroll
            for (int nf = 0; nf < 4; ++nf)
                #pragma unroll
                for (int kf = 0; kf < 2; ++kf)
                    acc[mf][nf] = __builtin_amdgcn_mfma_f32_16x16x32_bf16(af[mf][kf], bfr[nf][kf], acc[mf][nf], 0, 0, 0);
        __syncthreads();
    }

    // ---- store ----
    #pragma unroll
    for (int mf = 0; mf < 4; ++mf) {
        int pxb = wm * 64 + mf * 16 + l4 * 4;
        unsigned int gpix = p0 + pxb;
        #pragma unroll
        for (int nf = 0; nf < 4; ++nf) {
            int ch = n0 + wn * 64 + nf * 16 + l15;
            if (OUT_MODE == 0) {
                if (ch < DOUT) {
                    float* o = (float*)Out + (size_t)gpix * DOUT + ch;
                    #pragma unroll
                    for (int j = 0; j < 4; ++j) o[(size_t)j * DOUT] = acc[mf][nf][j];
                }
            } else if (OUT_MODE == 1) {
                if (ch < DOUT) {
                    unsigned short* o = (unsigned short*)Out + (size_t)gpix * DOUT + ch;
                    #pragma unroll
                    for (int j = 0; j < 4; ++j) o[(size_t)j * DOUT] = (unsigned short)f2bf(acc[mf][nf][j]);
                }
            } else {
                unsigned int n = gpix / HW;
                unsigned int rem = gpix - n * HW;
                float* o = (float*)Out + ((size_t)(n * 256 + ch)) * HW + rem;
                *(f32x4*)o = acc[mf][nf];
            }
        }
    }
}

// ---------------------------------------------------------------------------
// Grouped 3x3 conv, register-blocked 4 y-outputs/thread. bf16 NCHW output.
// ---------------------------------------------------------------------------
__global__ __launch_bounds__(256) void dwconv_kernel(const float* __restrict__ input,
                                                     const float* __restrict__ ref,
                                                     const float* __restrict__ dw_w,
                                                     const float* __restrict__ dw_b,
                                                     unsigned short* __restrict__ out) {
    int blk = blockIdx.x;
    int yt = blk % 14;
    int cb = (blk / 14) & 63;
    int n = blk / (14 * 64);
    int tid = threadIdx.x;
    int x = tid & 63;
    int c = cb * 4 + (tid >> 6);
    int y0 = yt * 4;

    const float* src = (c < 128) ? input : ref;
    int ch0 = (c < 128) ? (2 * c) : (2 * c - 256);

    float w[18];
    #pragma unroll
    for (int i = 0; i < 18; ++i) w[i] = dw_w[c * 18 + i];

    if (x < WID) {
        float bv = dw_b[c];
        float acc[4] = {bv, bv, bv, bv};
        #pragma unroll
        for (int ch = 0; ch < 2; ++ch) {
            const float* base = src + (size_t)(n * NCH + ch0 + ch) * HW;
            #pragma unroll
            for (int r = 0; r < 6; ++r) {
                int yy = y0 - 1 + r;
                bool vy = (yy >= 0) && (yy < HEI);
                const float* row = base + yy * WID;
                float lt = (vy && x > 0) ? row[x - 1] : 0.f;
                float md = vy ? row[x] : 0.f;
                float rt = (vy && x < WID - 1) ? row[x + 1] : 0.f;
                #pragma unroll
                for (int o = 0; o < 4; ++o) {
                    int ky = r - o;
                    if (ky >= 0 && ky < 3) {
                        acc[o] += lt * w[ch * 9 + ky * 3 + 0] + md * w[ch * 9 + ky * 3 + 1] + rt * w[ch * 9 + ky * 3 + 2];
                    }
                }
            }
        }
        unsigned short* o = out + (size_t)(n * NCH + c) * HW + y0 * WID + x;
        #pragma unroll
        for (int j = 0; j < 4; ++j) o[j * WID] = (unsigned short)f2bf(acc[j]);
    }
}

// ---------------------------------------------------------------------------
// Sampler: bilinear gather from fp32 xv (NHWC), bf16 om, writes bf16 sout.
// Phase 0: per (pix,g,pt) 4 weights + 4 packed indices -> LDS.
// Phase 1: thread owns 2 chunks of 8 channels; per corner 2x float4 gather,
//          f32x4 FMA (packed-fp32 eligible), zero conversions.
// ---------------------------------------------------------------------------
__global__ __launch_bounds__(256) void sample_kernel(const float* __restrict__ xv,
                                                     const unsigned short* __restrict__ om,
                                                     unsigned short* __restrict__ sout) {
    int blk = blockIdx.x;
    int n = blk / (HW / 16);
    int p0 = (blk % (HW / 16)) * 16;
    int tid = threadIdx.x;

    __shared__ __align__(16) float swt[1152][4];
    __shared__ __align__(8) ushort soff[1152][4];

    for (int i = tid; i < 1152; i += 256) {
        int pix = i / 72;
        int r = i % 72;
        int g = r / 9;
        int pt = r % 9;
        int glob = p0 + pix;
        int py = glob / WID, px = glob % WID;
        const unsigned short* ob = om + ((size_t)n * HW + glob) * 216 + g * 27;
        float ox = bf2f(ob[2 * pt]);
        float oy = bf2f(ob[2 * pt + 1]);
        float m = bf2f(ob[18 + pt]);
        float iy = (float)(py + pt / 3 - 1) + oy;
        float ix = (float)(px + pt % 3 - 1) + ox;
        float fy0 = floorf(iy), fx0 = floorf(ix);
        float fy = iy - fy0, fx = ix - fx0;
        int y0 = (int)fy0, x0 = (int)fx0;
        #pragma unroll
        for (int dy = 0; dy < 2; ++dy) {
            #pragma unroll
            for (int dx = 0; dx < 2; ++dx) {
                int yy = y0 + dy, xx = x0 + dx;
                bool valid = (yy >= 0) & (yy < HEI) & (xx >= 0) & (xx < WID);
                int yc = min(max(yy, 0), HEI - 1);
                int xc = min(max(xx, 0), WID - 1);
                float wv = (dy ? fy : 1.f - fy) * (dx ? fx : 1.f - fx) * m;
                swt[i][dy * 2 + dx] = valid ? wv : 0.f;
                soff[i][dy * 2 + dx] = (ushort)(yc * WID + xc);
            }
        }
    }
    __syncthreads();

    int pix = tid >> 4;
    int t16 = tid & 15;
    const float* xvb = xv + (size_t)n * HW * 256;
    unsigned short* so = sout + ((size_t)n * HW + p0 + pix) * 256;

    #pragma unroll
    for (int i = 0; i < 2; ++i) {
        int chunk = t16 + 16 * i;
        int g = chunk >> 2, c8 = chunk & 3;
        int widx = pix * 72 + g * 9;
        const float* xc = xvb + g * 32 + c8 * 8;
        f32x4 a0 = (f32x4){0.f, 0.f, 0.f, 0.f};
        f32x4 a1 = (f32x4){0.f, 0.f, 0.f, 0.f};
        #pragma unroll
        for (int pt = 0; pt < 9; ++pt) {
            float4 w = *(const float4*)&swt[widx + pt][0];
            ushort4 o = *(const ushort4*)&soff[widx + pt][0];
            const float* s0 = xc + (size_t)o.x * 256;
            const float* s1 = xc + (size_t)o.y * 256;
            const float* s2 = xc + (size_t)o.z * 256;
            const float* s3 = xc + (size_t)o.w * 256;
            f32x4 w0 = (f32x4){w.x, w.x, w.x, w.x};
            f32x4 w1 = (f32x4){w.y, w.y, w.y, w.y};
            f32x4 w2 = (f32x4){w.z, w.z, w.z, w.z};
            f32x4 w3 = (f32x4){w.w, w.w, w.w, w.w};
            a0 += w0 * *(const f32x4*)(s0) + w1 * *(const f32x4*)(s1) + w2 * *(const f32x4*)(s2) + w3 * *(const f32x4*)(s3);
            a1 += w0 * *(const f32x4*)(s0 + 4) + w1 * *(const f32x4*)(s1 + 4) + w2 * *(const f32x4*)(s2 + 4) + w3 * *(const f32x4*)(s3 + 4);
        }
        u16x8 st;
        #pragma unroll
        for (int j = 0; j < 4; ++j) st[j] = (unsigned short)f2bf(a0[j]);
        #pragma unroll
        for (int j = 0; j < 4; ++j) st[4 + j] = (unsigned short)f2bf(a1[j]);
        *(u16x8*)(so + g * 32 + c8 * 8) = st;
    }
}

extern "C" void kernel_launch(void* const* d_in, const int* in_sizes, int n_in,
                              void* d_out, int out_size, void* d_ws, size_t ws_size,
                              hipStream_t stream) {
    const float* ref     = (const float*)d_in[0];
    const float* input   = (const float*)d_in[1];
    const float* value_w = (const float*)d_in[2];
    const float* value_b = (const float*)d_in[3];
    const float* dw_w    = (const float*)d_in[4];
    const float* dw_b    = (const float*)d_in[5];
    const float* om_w    = (const float*)d_in[6];
    const float* om_b    = (const float*)d_in[7];
    const float* out_w   = (const float*)d_in[8];
    const float* out_b   = (const float*)d_in[9];
    float* out = (float*)d_out;

    char* ws = (char*)d_ws;
    float* xv            = (float*)ws;                               // 51.4 MB fp32
    unsigned short* dwb  = (unsigned short*)(ws + (size_t)MTOT * 256 * 4);          // 25.7 MB
    unsigned short* sout = (unsigned short*)(ws + (size_t)MTOT * 256 * 6);          // 25.7 MB
    unsigned short* omb  = (unsigned short*)(ws + (size_t)MTOT * 256 * 8);          // 21.7 MB
    char* wbase          = ws + (size_t)MTOT * 256 * 8 + (size_t)MTOT * 216 * 2;
    unsigned short* vw_bf   = (unsigned short*)(wbase);
    unsigned short* ow_bf   = (unsigned short*)(wbase + 131072);
    unsigned short* outw_bf = (unsigned short*)(wbase + 131072 + 110592);

    cvt_weights<<<728, 256, 0, stream>>>(value_w, om_w, out_w, vw_bf, ow_bf, outw_bf);
    gemm_kernel<256, 0, 0><<<(MTOT / 128) * 2, 256, 0, stream>>>(input, vw_bf, value_b, xv);
    dwconv_kernel<<<NB * 64 * 14, 256, 0, stream>>>(input, ref, dw_w, dw_b, dwb);
    gemm_kernel<216, 1, 1><<<(MTOT / 128) * 2, 256, 0, stream>>>(dwb, ow_bf, om_b, omb);
    sample_kernel<<<NB * (HW / 16), 256, 0, stream>>>(xv, omb, sout);
    gemm_kernel<256, 2, 2><<<(MTOT / 128) * 2, 256, 0, stream>>>(sout, outw_bf, out_b, out);
}

// Round 9
// 277.666 us; speedup vs baseline: 1.1912x; 1.1912x over previous
//
#include <hip/hip_runtime.h>

#define HW 3136
#define WID 56
#define HEI 56
#define NCH 256
#define NB 16
#define MTOT (NB * HW)   // 50176 flat pixels

typedef __attribute__((ext_vector_type(8))) short bf16x8;
typedef __attribute__((ext_vector_type(8))) unsigned short u16x8;
typedef __attribute__((ext_vector_type(4))) float f32x4;

__device__ __forceinline__ unsigned int f2bf(float f) {
    unsigned int x = __float_as_uint(f);
    return (x + 0x7fffu + ((x >> 16) & 1u)) >> 16;  // RNE
}
__device__ __forceinline__ float bf2f(unsigned short u) {
    return __uint_as_float(((unsigned int)u) << 16);
}

// ---------------------------------------------------------------------------
// Weight conversion fp32 -> bf16 (value_w 65536, om_w 55296, out_w 65536)
// ---------------------------------------------------------------------------
__global__ __launch_bounds__(256) void cvt_weights(const float* __restrict__ vw,
                                                   const float* __restrict__ ow,
                                                   const float* __restrict__ outw,
                                                   unsigned short* __restrict__ dvw,
                                                   unsigned short* __restrict__ dow,
                                                   unsigned short* __restrict__ doutw) {
    int i = blockIdx.x * 256 + threadIdx.x;
    if (i < 65536) dvw[i] = (unsigned short)f2bf(vw[i]);
    else if (i < 120832) dow[i - 65536] = (unsigned short)f2bf(ow[i - 65536]);
    else if (i < 186368) doutw[i - 120832] = (unsigned short)f2bf(outw[i - 120832]);
}

// ---------------------------------------------------------------------------
// MFMA bf16 GEMM over flat M=50176: out[m][d] = sum_k A[m][k]*W[d][k] + b[d]
// A is staged ONCE per 128-px M-tile (full K=256, 64 KB LDS); both 128-ch
// N-halves computed with an internal nt loop (B restaged, 16 KB).
//   A_MODE 0: A fp32 NCHW; A_MODE 1: A bf16 NCHW; A_MODE 2: A bf16 flat [m][256]
//   OUT_MODE 1: bf16 flat [m][DOUT] guarded; OUT_MODE 2: fp32 NCHW (f32x4 stores)
// 4 waves (2M x 2N), per-wave 64x64 per nt. XOR-swizzle byte ^= (row&7)<<4.
// ---------------------------------------------------------------------------
template <int DOUT, int A_MODE, int OUT_MODE>
__global__ __launch_bounds__(256, 2) void gemm_kernel(const void* __restrict__ Aptr,
                                                      const unsigned short* __restrict__ Bw,
                                                      const float* __restrict__ bias,
                                                      void* __restrict__ Out) {
    int p0 = blockIdx.x * 128;    // flat pixel base, 392 blocks
    int tid = threadIdx.x;
    int lane = tid & 63;
    int wv = tid >> 6;
    int wm = wv & 1, wn = wv >> 1;
    int l15 = lane & 15;
    int l4 = lane >> 4;

    extern __shared__ __align__(16) char lds[];   // 64 KB As + 16 KB Bs = 80 KB
    char* As = lds;
    char* Bs = lds + 65536;

    // ---- stage A: 128 px x 256 k, once ----
    if (A_MODE == 0 || A_MODE == 1) {
        int px = tid & 127, khalf = tid >> 7;
        unsigned int gpix = p0 + px;
        unsigned int n = gpix / HW;
        unsigned int rem = gpix - n * HW;
        #pragma unroll
        for (int h = 0; h < 16; ++h) {
            int k = khalf * 128 + h * 8;
            u16x8 v;
            if (A_MODE == 0) {
                const float* src = (const float*)Aptr + ((size_t)(n * 256 + k)) * HW + rem;
                #pragma unroll
                for (int j = 0; j < 8; ++j) v[j] = (unsigned short)f2bf(src[(size_t)j * HW]);
            } else {
                const unsigned short* src = (const unsigned short*)Aptr + ((size_t)(n * 256 + k)) * HW + rem;
                #pragma unroll
                for (int j = 0; j < 8; ++j) v[j] = src[(size_t)j * HW];
            }
            int byte = px * 512 + ((k * 2) ^ ((px & 7) << 4));
            *(u16x8*)(As + byte) = v;
        }
    } else {
        int row = tid >> 1, khalf = tid & 1;
        const unsigned short* src = (const unsigned short*)Aptr + (size_t)(p0 + row) * 256 + khalf * 128;
        #pragma unroll
        for (int h = 0; h < 16; ++h) {
            u16x8 v = *(const u16x8*)(src + h * 8);
            int k2 = (khalf * 128 + h * 8) * 2;
            int byte = row * 512 + (k2 ^ ((row & 7) << 4));
            *(u16x8*)(As + byte) = v;
        }
    }

    #pragma unroll
    for (int nt = 0; nt < 2; ++nt) {
        int n0 = nt * 128;

        f32x4 acc[4][4];
        #pragma unroll
        for (int nf = 0; nf < 4; ++nf) {
            int ch = n0 + wn * 64 + nf * 16 + l15;
            float bv = (DOUT == 256 || ch < DOUT) ? bias[ch] : 0.f;
            #pragma unroll
            for (int mf = 0; mf < 4; ++mf) acc[mf][nf] = (f32x4){bv, bv, bv, bv};
        }

        for (int t = 0; t < 4; ++t) {
            int k0 = t * 64;
            __syncthreads();   // Bs free to overwrite (also covers As readiness on first pass)
            // ---- stage B: 128 ch x 64 k ----
            {
                int bch = tid >> 1, kh = tid & 1;
                int ch = n0 + bch;
                bool valid = (DOUT == 256) || (ch < DOUT);
                const unsigned short* src = Bw + (size_t)ch * 256 + k0 + kh * 32;
                #pragma unroll
                for (int q = 0; q < 4; ++q) {
                    u16x8 v = (u16x8){0, 0, 0, 0, 0, 0, 0, 0};
                    if (valid) v = *(const u16x8*)(src + q * 8);
                    int k2 = (kh * 32 + q * 8) * 2;
                    int byte = bch * 128 + (k2 ^ ((bch & 7) << 4));
                    *(u16x8*)(Bs + byte) = v;
                }
            }
            __syncthreads();
            // ---- compute ----
            bf16x8 af[4][2], bfr[4][2];
            #pragma unroll
            for (int mf = 0; mf < 4; ++mf)
                #pragma unroll
                for (int kf = 0; kf < 2; ++kf) {
                    int row = wm * 64 + mf * 16 + l15;
                    int k2 = (k0 + kf * 32 + l4 * 8) * 2;
                    int byte = row * 512 + (k2 ^ ((row & 7) << 4));
                    af[mf][kf] = *(bf16x8*)(As + byte);
                }
            #pragma unroll
            for (int nf = 0; nf < 4; ++nf)
                #pragma unroll
                for (int kf = 0; kf < 2; ++kf) {
                    int row = wn * 64 + nf * 16 + l15;
                    int k2 = (kf * 32 + l4 * 8) * 2;
                    int byte = row * 128 + (k2 ^ ((row & 7) << 4));
                    bfr[nf][kf] = *(bf16x8*)(Bs + byte);
                }
            #pragma unroll
            for (int mf = 0; mf < 4; ++mf)
                #pragma unroll
                for (int nf = 0; nf < 4; ++nf)
                    #pragma unroll
                    for (int kf = 0; kf < 2; ++kf)
                        acc[mf][nf] = __builtin_amdgcn_mfma_f32_16x16x32_bf16(af[mf][kf], bfr[nf][kf], acc[mf][nf], 0, 0, 0);
        }

        // ---- store this N-half ----
        #pragma unroll
        for (int mf = 0; mf < 4; ++mf) {
            int pxb = wm * 64 + mf * 16 + l4 * 4;
            unsigned int gpix = p0 + pxb;
            #pragma unroll
            for (int nf = 0; nf < 4; ++nf) {
                int ch = n0 + wn * 64 + nf * 16 + l15;
                if (OUT_MODE == 1) {
                    if (DOUT == 256 || ch < DOUT) {
                        unsigned short* o = (unsigned short*)Out + (size_t)gpix * DOUT + ch;
                        #pragma unroll
                        for (int j = 0; j < 4; ++j) o[(size_t)j * DOUT] = (unsigned short)f2bf(acc[mf][nf][j]);
                    }
                } else {
                    unsigned int n = gpix / HW;
                    unsigned int rem = gpix - n * HW;
                    float* o = (float*)Out + ((size_t)(n * 256 + ch)) * HW + rem;
                    *(f32x4*)o = acc[mf][nf];
                }
            }
        }
    }
}

// ---------------------------------------------------------------------------
// Grouped 3x3 conv, register-blocked 4 y-outputs/thread. bf16 NCHW output.
// ---------------------------------------------------------------------------
__global__ __launch_bounds__(256) void dwconv_kernel(const float* __restrict__ input,
                                                     const float* __restrict__ ref,
                                                     const float* __restrict__ dw_w,
                                                     const float* __restrict__ dw_b,
                                                     unsigned short* __restrict__ out) {
    int blk = blockIdx.x;
    int yt = blk % 14;
    int cb = (blk / 14) & 63;
    int n = blk / (14 * 64);
    int tid = threadIdx.x;
    int x = tid & 63;
    int c = cb * 4 + (tid >> 6);
    int y0 = yt * 4;

    const float* src = (c < 128) ? input : ref;
    int ch0 = (c < 128) ? (2 * c) : (2 * c - 256);

    float w[18];
    #pragma unroll
    for (int i = 0; i < 18; ++i) w[i] = dw_w[c * 18 + i];

    if (x < WID) {
        float bv = dw_b[c];
        float acc[4] = {bv, bv, bv, bv};
        #pragma unroll
        for (int ch = 0; ch < 2; ++ch) {
            const float* base = src + (size_t)(n * NCH + ch0 + ch) * HW;
            #pragma unroll
            for (int r = 0; r < 6; ++r) {
                int yy = y0 - 1 + r;
                bool vy = (yy >= 0) && (yy < HEI);
                const float* row = base + yy * WID;
                float lt = (vy && x > 0) ? row[x - 1] : 0.f;
                float md = vy ? row[x] : 0.f;
                float rt = (vy && x < WID - 1) ? row[x + 1] : 0.f;
                #pragma unroll
                for (int o = 0; o < 4; ++o) {
                    int ky = r - o;
                    if (ky >= 0 && ky < 3) {
                        acc[o] += lt * w[ch * 9 + ky * 3 + 0] + md * w[ch * 9 + ky * 3 + 1] + rt * w[ch * 9 + ky * 3 + 2];
                    }
                }
            }
        }
        unsigned short* o = out + (size_t)(n * NCH + c) * HW + y0 * WID + x;
        #pragma unroll
        for (int j = 0; j < 4; ++j) o[j * WID] = (unsigned short)f2bf(acc[j]);
    }
}

// ---------------------------------------------------------------------------
// Sampler: bilinear gather from bf16 xv (flat [m][256]), bf16 om, bf16 sout.
// Phase 0: per (pix,g,pt) 4 weights + 4 packed indices -> LDS.
// Phase 1 (round-5 proven): thread owns 2 chunks of 8 channels; per corner
//          one 16 B u16x8 gather; scalar bf2f FMA into fp32 acc.
// ---------------------------------------------------------------------------
__global__ __launch_bounds__(256) void sample_kernel(const unsigned short* __restrict__ xv,
                                                     const unsigned short* __restrict__ om,
                                                     unsigned short* __restrict__ sout) {
    int blk = blockIdx.x;
    int n = blk / (HW / 16);
    int p0 = (blk % (HW / 16)) * 16;
    int tid = threadIdx.x;

    __shared__ __align__(16) float swt[1152][4];
    __shared__ __align__(8) ushort soff[1152][4];

    for (int i = tid; i < 1152; i += 256) {
        int pix = i / 72;
        int r = i % 72;
        int g = r / 9;
        int pt = r % 9;
        int glob = p0 + pix;
        int py = glob / WID, px = glob % WID;
        const unsigned short* ob = om + ((size_t)n * HW + glob) * 216 + g * 27;
        float ox = bf2f(ob[2 * pt]);
        float oy = bf2f(ob[2 * pt + 1]);
        float m = bf2f(ob[18 + pt]);
        float iy = (float)(py + pt / 3 - 1) + oy;
        float ix = (float)(px + pt % 3 - 1) + ox;
        float fy0 = floorf(iy), fx0 = floorf(ix);
        float fy = iy - fy0, fx = ix - fx0;
        int y0 = (int)fy0, x0 = (int)fx0;
        #pragma unroll
        for (int dy = 0; dy < 2; ++dy) {
            #pragma unroll
            for (int dx = 0; dx < 2; ++dx) {
                int yy = y0 + dy, xx = x0 + dx;
                bool valid = (yy >= 0) & (yy < HEI) & (xx >= 0) & (xx < WID);
                int yc = min(max(yy, 0), HEI - 1);
                int xc = min(max(xx, 0), WID - 1);
                float wv = (dy ? fy : 1.f - fy) * (dx ? fx : 1.f - fx) * m;
                swt[i][dy * 2 + dx] = valid ? wv : 0.f;
                soff[i][dy * 2 + dx] = (ushort)(yc * WID + xc);
            }
        }
    }
    __syncthreads();

    int pix = tid >> 4;
    int t16 = tid & 15;
    const unsigned short* xvb = xv + (size_t)n * HW * 256;
    unsigned short* so = sout + ((size_t)n * HW + p0 + pix) * 256;

    #pragma unroll
    for (int i = 0; i < 2; ++i) {
        int chunk = t16 + 16 * i;
        int g = chunk >> 2, c8 = chunk & 3;
        int widx = pix * 72 + g * 9;
        const unsigned short* xc = xvb + g * 32 + c8 * 8;
        float acc[8];
        #pragma unroll
        for (int j = 0; j < 8; ++j) acc[j] = 0.f;
        #pragma unroll
        for (int pt = 0; pt < 9; ++pt) {
            float4 w = *(const float4*)&swt[widx + pt][0];
            ushort4 o = *(const ushort4*)&soff[widx + pt][0];
            u16x8 r0 = *(const u16x8*)(xc + (size_t)o.x * 256);
            u16x8 r1 = *(const u16x8*)(xc + (size_t)o.y * 256);
            u16x8 r2 = *(const u16x8*)(xc + (size_t)o.z * 256);
            u16x8 r3 = *(const u16x8*)(xc + (size_t)o.w * 256);
            #pragma unroll
            for (int j = 0; j < 8; ++j) {
                acc[j] += w.x * bf2f(r0[j]) + w.y * bf2f(r1[j]) + w.z * bf2f(r2[j]) + w.w * bf2f(r3[j]);
            }
        }
        u16x8 st;
        #pragma unroll
        for (int j = 0; j < 8; ++j) st[j] = (unsigned short)f2bf(acc[j]);
        *(u16x8*)(so + g * 32 + c8 * 8) = st;
    }
}

extern "C" void kernel_launch(void* const* d_in, const int* in_sizes, int n_in,
                              void* d_out, int out_size, void* d_ws, size_t ws_size,
                              hipStream_t stream) {
    const float* ref     = (const float*)d_in[0];
    const float* input   = (const float*)d_in[1];
    const float* value_w = (const float*)d_in[2];
    const float* value_b = (const float*)d_in[3];
    const float* dw_w    = (const float*)d_in[4];
    const float* dw_b    = (const float*)d_in[5];
    const float* om_w    = (const float*)d_in[6];
    const float* om_b    = (const float*)d_in[7];
    const float* out_w   = (const float*)d_in[8];
    const float* out_b   = (const float*)d_in[9];
    float* out = (float*)d_out;

    char* ws = (char*)d_ws;
    const size_t BF = (size_t)MTOT * 256 * 2;            // 25.7 MB per bf16 tensor
    unsigned short* xv   = (unsigned short*)(ws);
    unsigned short* dwb  = (unsigned short*)(ws + BF);
    unsigned short* sout = (unsigned short*)(ws + 2 * BF);
    unsigned short* omb  = (unsigned short*)(ws + 3 * BF);   // [m][216] bf16, 21.7 MB
    char* wbase          = ws + 3 * BF + (size_t)MTOT * 216 * 2;
    unsigned short* vw_bf   = (unsigned short*)(wbase);
    unsigned short* ow_bf   = (unsigned short*)(wbase + 131072);
    unsigned short* outw_bf = (unsigned short*)(wbase + 131072 + 110592);

    const size_t GEMM_LDS = 65536 + 16384;   // 80 KB dynamic

    cvt_weights<<<728, 256, 0, stream>>>(value_w, om_w, out_w, vw_bf, ow_bf, outw_bf);
    gemm_kernel<256, 0, 1><<<MTOT / 128, 256, GEMM_LDS, stream>>>(input, vw_bf, value_b, xv);
    dwconv_kernel<<<NB * 64 * 14, 256, 0, stream>>>(input, ref, dw_w, dw_b, dwb);
    gemm_kernel<216, 1, 1><<<MTOT / 128, 256, GEMM_LDS, stream>>>(dwb, ow_bf, om_b, omb);
    sample_kernel<<<NB * (HW / 16), 256, 0, stream>>>(xv, omb, sout);
    gemm_kernel<256, 2, 2><<<MTOT / 128, 256, GEMM_LDS, stream>>>(sout, outw_bf, out_b, out);
}